// Round 18
// baseline (62.764 us; speedup 1.0000x reference)
//
#include <hip/hip_runtime.h>
#include <hip/hip_bf16.h>

#define M_ROWS 256
#define T_LEN  1024
#define NLAG   2048
#define CPYB   656    // bytes per copy slot = 16*41 (16B-aligned bases); 164 words == 4 mod 32
#define CPCH   39     // 16B chunks of data per copy (39*16 = 624)
#define NCOPY4 32
#define GPZW4  260    // u32 words per padded fp4 row (128 data | 128 zero | 4 wrap)

typedef __attribute__((ext_vector_type(4)))  unsigned int u32x4;
typedef __attribute__((ext_vector_type(8)))  int          i32x8;
typedef __attribute__((ext_vector_type(16))) float        f32x16;

static __device__ __forceinline__ unsigned short f2bf(float f) {
  unsigned int u = __builtin_bit_cast(unsigned int, f);
  u += 0x7FFFu + ((u >> 16) & 1u);   // RNE
  return (unsigned short)(u >> 16);
}

// nearest fp4 e2m1 level: {0,.5,1,1.5,2,3,4,6}, midpoint thresholds
static __device__ __forceinline__ unsigned int fp4enc(float c) {
  float a = fabsf(c);
  unsigned int code = (unsigned int)(a >= 0.25f) + (unsigned int)(a >= 0.75f) +
                      (unsigned int)(a >= 1.25f) + (unsigned int)(a >= 1.75f) +
                      (unsigned int)(a >= 2.5f)  + (unsigned int)(a >= 3.5f) +
                      (unsigned int)(a >= 5.0f);
  return code | ((__builtin_bit_cast(unsigned int, c) >> 28) & 8u);
}

// ---------------- prep: center rows, fp4-ify, std(ddof=1) ----------------
// f1 -> packed fp4 fragments f1p4[[ks][l5][row][4w]]; f2 -> padded fp4 rows gpz4[256][260w]
__global__ __launch_bounds__(256) void prep_kernel(
    const float* __restrict__ zis, const float* __restrict__ zjs,
    unsigned int* __restrict__ f1p4, unsigned int* __restrict__ gpz4,
    float* __restrict__ s1, float* __restrict__ s2, float* __restrict__ out) {
  int r = blockIdx.x;  // 0..511
  const float* src = (r < M_ROWS) ? (zis + r * T_LEN) : (zjs + (r - M_ROWS) * T_LEN);
  int t = threadIdx.x;
  if (r == 0 && t == 0) out[0] = 0.0f;
  float4 v = reinterpret_cast<const float4*>(src)[t];
  float ls = v.x + v.y + v.z + v.w;
  for (int m = 1; m <= 32; m <<= 1) ls += __shfl_xor(ls, m, 64);
  __shared__ float red[4];
  __shared__ float red2[4];
  if ((t & 63) == 0) red[t >> 6] = ls;
  __syncthreads();
  float mean = (red[0] + red[1] + red[2] + red[3]) * (1.0f / 1024.0f);
  float c0 = v.x - mean, c1 = v.y - mean, c2 = v.z - mean, c3 = v.w - mean;
  float ss = c0 * c0 + c1 * c1 + c2 * c2 + c3 * c3;
  for (int m = 1; m <= 32; m <<= 1) ss += __shfl_xor(ss, m, 64);
  if ((t & 63) == 0) red2[t >> 6] = ss;
  __syncthreads();
  float sd = sqrtf((red2[0] + red2[1] + red2[2] + red2[3]) * (1.0f / 1023.0f));

  unsigned int h16 = fp4enc(c0) | (fp4enc(c1) << 4) | (fp4enc(c2) << 8) | (fp4enc(c3) << 12);
  unsigned int other = (unsigned int)__shfl_xor((int)h16, 1, 64);
  unsigned int word = h16 | (other << 16);   // valid on even t: elems 8*(t/2)..+7

  if (r < M_ROWS) {
    if (t == 0) s1[r] = sd;
    if (!(t & 1)) {
      int ks = t >> 4, l5 = (t >> 3) & 1, w = (t & 7) >> 1;
      f1p4[((ks * 2 + l5) * 256 + r) * 4 + w] = word;
    }
  } else {
    int j = r - M_ROWS;
    if (t == 0) s2[j] = sd;
    if (!(t & 1)) gpz4[j * GPZW4 + (t >> 1)] = word;       // data words 0..127
    if (t >= 128) gpz4[j * GPZW4 + t] = 0u;                // zero words 128..255
    if (!(t & 1) && (t >> 1) < 4) gpz4[j * GPZW4 + 256 + (t >> 1)] = word;  // wrap tail
  }
}

// bump-pointer F loads (fp4 MFMA reads only the low 4 regs; insert-style, non-spilling)
#define LOADF_P(F0, F1)                                   \
  {                                                       \
    ((u32x4*)&(F0))[0] = *(const u32x4*)(fp);             \
    ((u32x4*)&(F1))[0] = *(const u32x4*)(fp + 128);       \
    fp += 2048;                                           \
  }

// 2 G frags from one running byte offset; lf=0 at +16, lf=1 at +0; advance one k-step
#define LDG2A(GA, GB)                                               \
  {                                                                 \
    ((u32x4*)&(GA))[0] = *(const u32x4*)(ldsB + gb + 16);           \
    ((u32x4*)&(GB))[0] = *(const u32x4*)(ldsB + gb);                \
    gb += 32;                                                       \
  }

// 4 MFMA (fp4 fmt=4): lag frags GA,GB; row frags F0 (+0..31), F1 (+32..63)
#define STEP4(GA, GB, F0, F1)                                                                \
  {                                                                                          \
    z00 = __builtin_amdgcn_mfma_scale_f32_32x32x64_f8f6f4(GA, F0, z00, 4, 4, 0, 127, 0, 127); \
    z10 = __builtin_amdgcn_mfma_scale_f32_32x32x64_f8f6f4(GA, F1, z10, 4, 4, 0, 127, 0, 127); \
    z01 = __builtin_amdgcn_mfma_scale_f32_32x32x64_f8f6f4(GB, F0, z01, 4, 4, 0, 127, 0, 127); \
    z11 = __builtin_amdgcn_mfma_scale_f32_32x32x64_f8f6f4(GB, F1, z11, 4, 4, 0, 127, 0, 127); \
  }

// ---------------- Toeplitz-GEMM correlation (MX-fp4, 64x64 wave tile, 3 waves/SIMD) ----
// grid: wg = ((bp*2+lh)*256) + j ; 4096 wgs, 256 threads = 4 waves (wave rw = row quarter).
// wg does lag-half lh of blk pair (bp, bp+8): 18 k64-steps, uniform. Wave tile 64r x 64l.
// acc = 4 x f32x16 = 64 AGPR -> ~148 total regs -> 3 waves/SIMD (the point of this round).
// Copy cp: g_cp[x] = gp[(x-cp) mod 2048], x in [-96,1152). byte(ks,l5,lf,pc) =
//   32ks + 16l5 - 16lf - 64bp - 32lh + 48 + 512pc  (proven in [0,624]).
__global__ __launch_bounds__(256, 3) void corr_kernel(
    const unsigned int* __restrict__ f1p4,
    const unsigned int* __restrict__ gpz4,
    unsigned short* __restrict__ part) {
  __shared__ __align__(16) unsigned char ldsB[NCOPY4 * CPYB];   // 20992 B
  __shared__ float red[2][256];                                 // phase-parity dbuf

  int wg = blockIdx.x;
  int j = wg & 255;
  int bh = wg >> 8;         // 0..15
  int bp = bh >> 1;         // 0..7
  int lh = bh & 1;          // lag half

  int tid = threadIdx.x;
  int lane = tid & 63;
  int rw = tid >> 6;        // wave id = row quarter
  int l5 = lane >> 5;
  int l31 = lane & 31;

  // ---- build 32 range-compressed fp4 copies: 1248 16B chunks ----
  {
    const unsigned int* gj = gpz4 + j * GPZW4;
#pragma unroll
    for (int m = 0; m < 5; ++m) {
      int ch = m * 256 + tid;
      if (ch < NCOPY4 * CPCH) {
        int cp = ch / CPCH;           // magic-mul
        int cc = ch - cp * CPCH;
        int s = 32 * cc - 96 - cp;    // source elem of chunk start: x0 - cp
        int m0 = s + ((s < 0) ? 2048 : 0);
        int wb = m0 >> 3;
        int sh = (m0 & 7) << 2;
        unsigned int w0 = gj[wb], w1 = gj[wb + 1], w2 = gj[wb + 2],
                     w3 = gj[wb + 3], w4 = gj[wb + 4];
        u32x4 o;
        if (sh) {
          o[0] = (w0 >> sh) | (w1 << (32 - sh));
          o[1] = (w1 >> sh) | (w2 << (32 - sh));
          o[2] = (w2 >> sh) | (w3 << (32 - sh));
          o[3] = (w3 >> sh) | (w4 << (32 - sh));
        } else {
          o[0] = w0; o[1] = w1; o[2] = w2; o[3] = w3;
        }
        *reinterpret_cast<u32x4*>(ldsB + cp * CPYB + cc * 16) = o;
      }
    }
  }
  __syncthreads();

  // F (rows, MFMA-B): word idx ((ks*2+l5)*256 + row)*4
  const unsigned int* fbase = f1p4 + l5 * 1024 + ((rw * 64 + l31) << 2);
  // G base byte at lf=1, ks=kA for pc0: l31*CPYB + 16*l5 - 32*lh + 32
  int gb_lane = l31 * CPYB + 16 * l5 - 32 * lh + 32;

#pragma unroll 1
  for (int pc = 0; pc < 2; ++pc) {
    int blk = pc ? (bp + 8) : bp;
    int kA = pc ? 0 : (bp << 1);
    int kB = pc ? ((bp << 1) + 2) : 16;
    // n = kB - kA even, >= 2

    int gb = gb_lane + (pc ? (512 - 64 * bp) : 0);
    const unsigned int* fp = fbase + kA * 2048;

    f32x16 z00, z01, z10, z11;  // z[lag-frag][row-half]
#pragma unroll
    for (int q = 0; q < 16; ++q) { z00[q] = 0.f; z01[q] = 0.f; z10[q] = 0.f; z11[q] = 0.f; }

    i32x8 XA = {0,0,0,0,0,0,0,0}, XB = {0,0,0,0,0,0,0,0};
    i32x8 YA = {0,0,0,0,0,0,0,0}, YB = {0,0,0,0,0,0,0,0};
    i32x8 Fx0 = {0,0,0,0,0,0,0,0}, Fx1 = {0,0,0,0,0,0,0,0};
    i32x8 Fy0 = {0,0,0,0,0,0,0,0}, Fy1 = {0,0,0,0,0,0,0,0};

    LDG2A(XA, XB);
    LOADF_P(Fx0, Fx1);
    int ks = kA;
#pragma unroll 1
    for (; ks + 2 < kB; ks += 2) {
      LDG2A(YA, YB);                      // prefetch ks+1 BEFORE consuming ks
      LOADF_P(Fy0, Fy1);
      STEP4(XA, XB, Fx0, Fx1);            // ks
      LDG2A(XA, XB);                      // prefetch ks+2
      LOADF_P(Fx0, Fx1);
      STEP4(YA, YB, Fy0, Fy1);            // ks+1
    }
    LDG2A(YA, YB);
    LOADF_P(Fy0, Fy1);
    STEP4(XA, XB, Fx0, Fx1);
    STEP4(YA, YB, Fy0, Fy1);

    // ---- per-row max: lags lane-local -> in-register fold + 1 shuffle ----
    float a0 = fmaxf(z00[0], z01[0]);
    float a1 = fmaxf(z10[0], z11[0]);
#pragma unroll
    for (int q = 1; q < 16; ++q) {
      a0 = fmaxf(a0, fmaxf(z00[q], z01[q]));
      a1 = fmaxf(a1, fmaxf(z10[q], z11[q]));
    }
    a0 = fmaxf(a0, __shfl_xor(a0, 32, 64));
    a1 = fmaxf(a1, __shfl_xor(a1, 32, 64));
    if (l5 == 0) {
      red[pc][rw * 64 + l31] = a0;        // rows rw*64 + 0..31
      red[pc][rw * 64 + 32 + l31] = a1;   // rows rw*64 + 32..63
    }
    __syncthreads();
    part[(tid * 32 + blk * 2 + lh) * 256 + j] = f2bf(red[pc][tid]);
    // no 2nd barrier: next phase writes red[pc^1]; ordering via next phase's barrier
  }
}

// ---------------- per-row CE: dist, logsumexp, pick target; atomic sum ----------------
__global__ __launch_bounds__(256) void loss_kernel(
    const unsigned short* __restrict__ part, const float* __restrict__ s1,
    const float* __restrict__ s2, const int* __restrict__ speeds,
    float* __restrict__ out) {
  int i = blockIdx.x;
  int jt = threadIdx.x;
  unsigned short um = part[(i * 32 + 0) * 256 + jt];
  float m = __builtin_bit_cast(float, ((unsigned int)um) << 16);
#pragma unroll
  for (int b = 1; b < 32; ++b) {
    unsigned short ub = part[(i * 32 + b) * 256 + jt];
    m = fmaxf(m, __builtin_bit_cast(float, ((unsigned int)ub) << 16));
  }
  float p = s1[i] * s2[jt];
  p = (p == 0.0f) ? 1.0f : p;
  float d = m / (p * 1023.0f);

  float t = d;
  for (int mk = 1; mk <= 32; mk <<= 1) t = fmaxf(t, __shfl_xor(t, mk, 64));
  __shared__ float wmax[4], wsum[4], sel;
  if ((jt & 63) == 0) wmax[jt >> 6] = t;
  if (jt == speeds[i]) sel = d;
  __syncthreads();
  float rmax = fmaxf(fmaxf(wmax[0], wmax[1]), fmaxf(wmax[2], wmax[3]));
  float e = expf(d - rmax);
  for (int mk = 1; mk <= 32; mk <<= 1) e += __shfl_xor(e, mk, 64);
  if ((jt & 63) == 0) wsum[jt >> 6] = e;
  __syncthreads();
  if (jt == 0) {
    float sum = wsum[0] + wsum[1] + wsum[2] + wsum[3];
    atomicAdd(out, rmax + logf(sum) - sel);
  }
}

extern "C" void kernel_launch(void* const* d_in, const int* in_sizes, int n_in,
                              void* d_out, int out_size, void* d_ws, size_t ws_size,
                              hipStream_t stream) {
  (void)in_sizes; (void)n_in; (void)out_size; (void)ws_size;
  const float* zis = (const float*)d_in[0];
  const float* zjs = (const float*)d_in[1];
  const int* speeds = (const int*)d_in[2];
  float* out = (float*)d_out;

  char* ws = (char*)d_ws;
  unsigned int* f1p4 = (unsigned int*)ws;                          // 128 KB packed fp4 A
  unsigned int* gpz4 = (unsigned int*)(ws + 131072);               // 260 KB padded fp4 rows
  float* s1 = (float*)(ws + 131072 + 266240);                      // 1 KB
  float* s2 = (float*)(ws + 131072 + 266240 + 1024);               // 1 KB
  unsigned short* part = (unsigned short*)(ws + 131072 + 266240 + 2048);  // 4 MB bf16 [i][32][j]

  prep_kernel<<<512, 256, 0, stream>>>(zis, zjs, f1p4, gpz4, s1, s2, out);
  corr_kernel<<<4096, 256, 0, stream>>>(f1p4, gpz4, part);
  loss_kernel<<<256, 256, 0, stream>>>(part, s1, s2, speeds, out);
}

// Round 19
// 52.904 us; speedup vs baseline: 1.1864x; 1.1864x over previous
//
#include <hip/hip_runtime.h>
#include <hip/hip_bf16.h>

#define M_ROWS 256
#define T_LEN  1024
#define NLAG   2048
#define CPYB   656    // bytes per copy slot = 16*41 (16B-aligned bases); 164 words == 4 mod 32
#define CPCH   39     // 16B chunks of data per copy (39*16 = 624)
#define NCOPY4 32
#define GPZW4  260    // u32 words per padded fp4 row (128 data | 128 zero | 4 wrap)

typedef __attribute__((ext_vector_type(4)))  unsigned int u32x4;
typedef __attribute__((ext_vector_type(8)))  int          i32x8;
typedef __attribute__((ext_vector_type(16))) float        f32x16;

static __device__ __forceinline__ unsigned short f2bf(float f) {
  unsigned int u = __builtin_bit_cast(unsigned int, f);
  u += 0x7FFFu + ((u >> 16) & 1u);   // RNE
  return (unsigned short)(u >> 16);
}

// nearest fp4 e2m1 level: {0,.5,1,1.5,2,3,4,6}, midpoint thresholds
static __device__ __forceinline__ unsigned int fp4enc(float c) {
  float a = fabsf(c);
  unsigned int code = (unsigned int)(a >= 0.25f) + (unsigned int)(a >= 0.75f) +
                      (unsigned int)(a >= 1.25f) + (unsigned int)(a >= 1.75f) +
                      (unsigned int)(a >= 2.5f)  + (unsigned int)(a >= 3.5f) +
                      (unsigned int)(a >= 5.0f);
  return code | ((__builtin_bit_cast(unsigned int, c) >> 28) & 8u);
}

// ---------------- prep: center rows, fp4-ify, std(ddof=1) ----------------
// f1 -> packed fp4 fragments f1p4[[ks][l5][row][4w]]; f2 -> padded fp4 rows gpz4[256][260w]
__global__ __launch_bounds__(256) void prep_kernel(
    const float* __restrict__ zis, const float* __restrict__ zjs,
    unsigned int* __restrict__ f1p4, unsigned int* __restrict__ gpz4,
    float* __restrict__ s1, float* __restrict__ s2, float* __restrict__ out) {
  int r = blockIdx.x;  // 0..511
  const float* src = (r < M_ROWS) ? (zis + r * T_LEN) : (zjs + (r - M_ROWS) * T_LEN);
  int t = threadIdx.x;
  if (r == 0 && t == 0) out[0] = 0.0f;
  float4 v = reinterpret_cast<const float4*>(src)[t];
  float ls = v.x + v.y + v.z + v.w;
  for (int m = 1; m <= 32; m <<= 1) ls += __shfl_xor(ls, m, 64);
  __shared__ float red[4];
  __shared__ float red2[4];
  if ((t & 63) == 0) red[t >> 6] = ls;
  __syncthreads();
  float mean = (red[0] + red[1] + red[2] + red[3]) * (1.0f / 1024.0f);
  float c0 = v.x - mean, c1 = v.y - mean, c2 = v.z - mean, c3 = v.w - mean;
  float ss = c0 * c0 + c1 * c1 + c2 * c2 + c3 * c3;
  for (int m = 1; m <= 32; m <<= 1) ss += __shfl_xor(ss, m, 64);
  if ((t & 63) == 0) red2[t >> 6] = ss;
  __syncthreads();
  float sd = sqrtf((red2[0] + red2[1] + red2[2] + red2[3]) * (1.0f / 1023.0f));

  unsigned int h16 = fp4enc(c0) | (fp4enc(c1) << 4) | (fp4enc(c2) << 8) | (fp4enc(c3) << 12);
  unsigned int other = (unsigned int)__shfl_xor((int)h16, 1, 64);
  unsigned int word = h16 | (other << 16);   // valid on even t: elems 8*(t/2)..+7

  if (r < M_ROWS) {
    if (t == 0) s1[r] = sd;
    if (!(t & 1)) {
      int ks = t >> 4, l5 = (t >> 3) & 1, w = (t & 7) >> 1;
      f1p4[((ks * 2 + l5) * 256 + r) * 4 + w] = word;
    }
  } else {
    int j = r - M_ROWS;
    if (t == 0) s2[j] = sd;
    if (!(t & 1)) gpz4[j * GPZW4 + (t >> 1)] = word;       // data words 0..127
    if (t >= 128) gpz4[j * GPZW4 + t] = 0u;                // zero words 128..255
    if (!(t & 1) && (t >> 1) < 4) gpz4[j * GPZW4 + 256 + (t >> 1)] = word;  // wrap tail
  }
}

// bump-pointer F loads (fp4 MFMA reads only the low 4 regs; insert-style, non-spilling)
#define LOADF_P(F0, F1)                                   \
  {                                                       \
    ((u32x4*)&(F0))[0] = *(const u32x4*)(fp);             \
    ((u32x4*)&(F1))[0] = *(const u32x4*)(fp + 128);       \
    fp += 2048;                                           \
  }

// 4 G frags from one running byte offset; LF=0..3 at +48,+32,+16,+0; then advance one k-step
#define LDG4A(GA, GB, GC, GD)                                       \
  {                                                                 \
    ((u32x4*)&(GA))[0] = *(const u32x4*)(ldsB + gb + 48);           \
    ((u32x4*)&(GB))[0] = *(const u32x4*)(ldsB + gb + 32);           \
    ((u32x4*)&(GC))[0] = *(const u32x4*)(ldsB + gb + 16);           \
    ((u32x4*)&(GD))[0] = *(const u32x4*)(ldsB + gb);                \
    gb += 32;                                                       \
  }

// 8 MFMA (fp4 fmt=4): lag frags GA..GD = lf0..3, row frags F0 (+0..31), F1 (+32..63)
// setprio(1) around the MFMA burst (pays when waves are desynced -> R19's stagger)
#define STEP8(GA, GB, GC, GD, F0, F1)                                                        \
  {                                                                                          \
    __builtin_amdgcn_s_setprio(1);                                                           \
    z00 = __builtin_amdgcn_mfma_scale_f32_32x32x64_f8f6f4(GA, F0, z00, 4, 4, 0, 127, 0, 127); \
    z10 = __builtin_amdgcn_mfma_scale_f32_32x32x64_f8f6f4(GA, F1, z10, 4, 4, 0, 127, 0, 127); \
    z01 = __builtin_amdgcn_mfma_scale_f32_32x32x64_f8f6f4(GB, F0, z01, 4, 4, 0, 127, 0, 127); \
    z11 = __builtin_amdgcn_mfma_scale_f32_32x32x64_f8f6f4(GB, F1, z11, 4, 4, 0, 127, 0, 127); \
    z02 = __builtin_amdgcn_mfma_scale_f32_32x32x64_f8f6f4(GC, F0, z02, 4, 4, 0, 127, 0, 127); \
    z12 = __builtin_amdgcn_mfma_scale_f32_32x32x64_f8f6f4(GC, F1, z12, 4, 4, 0, 127, 0, 127); \
    z03 = __builtin_amdgcn_mfma_scale_f32_32x32x64_f8f6f4(GD, F0, z03, 4, 4, 0, 127, 0, 127); \
    z13 = __builtin_amdgcn_mfma_scale_f32_32x32x64_f8f6f4(GD, F1, z13, 4, 4, 0, 127, 0, 127); \
    __builtin_amdgcn_s_setprio(0);                                                           \
  }

// ---------------- Toeplitz-GEMM correlation (MX-fp4, range-compressed copies) ----------
// grid: wg = bp*256 + j ; 2048 wgs, 256 threads = 4 waves (wave rw = row quarter).
// wg does blk pair (bp, bp+8): 18 k64-steps, uniform. Wave tile 64 rows x 128 lags.
// R19: phase ORDER staggered by j parity (odd j runs short phase first) to decorrelate
// the two resident wgs' stall windows; setprio(1) favors the MFMA-bursting wave.
__global__ __launch_bounds__(256, 2) void corr_kernel(
    const unsigned int* __restrict__ f1p4,
    const unsigned int* __restrict__ gpz4,
    unsigned short* __restrict__ part) {
  __shared__ __align__(16) unsigned char ldsB[NCOPY4 * CPYB];   // 20992 B
  __shared__ float red[2][256];                                 // phase-indexed dbuf

  int wg = blockIdx.x;
  int j = wg & 255;
  int bp = wg >> 8;         // 0..7

  int tid = threadIdx.x;
  int lane = tid & 63;
  int rw = tid >> 6;        // wave id = row quarter
  int l5 = lane >> 5;
  int l31 = lane & 31;

  // ---- build 32 range-compressed fp4 copies: 1248 16B chunks ----
  {
    const unsigned int* gj = gpz4 + j * GPZW4;
#pragma unroll
    for (int m = 0; m < 5; ++m) {
      int ch = m * 256 + tid;
      if (ch < NCOPY4 * CPCH) {
        int cp = ch / CPCH;           // magic-mul
        int cc = ch - cp * CPCH;
        int s = 32 * cc - 96 - cp;    // source elem of chunk start: x0 - cp
        int m0 = s + ((s < 0) ? 2048 : 0);
        int wb = m0 >> 3;
        int sh = (m0 & 7) << 2;
        unsigned int w0 = gj[wb], w1 = gj[wb + 1], w2 = gj[wb + 2],
                     w3 = gj[wb + 3], w4 = gj[wb + 4];
        u32x4 o;
        if (sh) {
          o[0] = (w0 >> sh) | (w1 << (32 - sh));
          o[1] = (w1 >> sh) | (w2 << (32 - sh));
          o[2] = (w2 >> sh) | (w3 << (32 - sh));
          o[3] = (w3 >> sh) | (w4 << (32 - sh));
        } else {
          o[0] = w0; o[1] = w1; o[2] = w2; o[3] = w3;
        }
        *reinterpret_cast<u32x4*>(ldsB + cp * CPYB + cc * 16) = o;
      }
    }
  }
  __syncthreads();

  // F (rows, MFMA-B): word idx ((ks*2+l5)*256 + row)*4
  const unsigned int* fbase = f1p4 + l5 * 1024 + ((rw * 64 + l31) << 2);
  int gb_lane = l31 * CPYB + 16 * l5;   // per-lane G base (LF=3 byte addr at phase start)

  int first = j & 1;  // stagger: odd j runs the short phase (pc=1) first
#pragma unroll 1
  for (int pi = 0; pi < 2; ++pi) {
    int pc = pi ^ first;
    int blk = pc ? (bp + 8) : bp;
    int kA = pc ? 0 : (bp << 1);
    int kB = pc ? ((bp << 1) + 2) : 16;
    // n = kB - kA even, >= 2

    // running byte offset for LF=3 at current ks: +32 B per k-step
    int gb = gb_lane + (pc ? (512 - 64 * bp) : 0);
    const unsigned int* fp = fbase + kA * 2048;

    f32x16 z00, z01, z02, z03, z10, z11, z12, z13;
#pragma unroll
    for (int q = 0; q < 16; ++q) {
      z00[q] = 0.f; z01[q] = 0.f; z02[q] = 0.f; z03[q] = 0.f;
      z10[q] = 0.f; z11[q] = 0.f; z12[q] = 0.f; z13[q] = 0.f;
    }

    i32x8 X0 = {0,0,0,0,0,0,0,0}, X1 = {0,0,0,0,0,0,0,0};
    i32x8 X2 = {0,0,0,0,0,0,0,0}, X3 = {0,0,0,0,0,0,0,0};
    i32x8 Y0 = {0,0,0,0,0,0,0,0}, Y1 = {0,0,0,0,0,0,0,0};
    i32x8 Y2 = {0,0,0,0,0,0,0,0}, Y3 = {0,0,0,0,0,0,0,0};
    i32x8 Fx0 = {0,0,0,0,0,0,0,0}, Fx1 = {0,0,0,0,0,0,0,0};
    i32x8 Fy0 = {0,0,0,0,0,0,0,0}, Fy1 = {0,0,0,0,0,0,0,0};

    LDG4A(X0, X1, X2, X3);
    LOADF_P(Fx0, Fx1);
    int ks = kA;
#pragma unroll 1
    for (; ks + 2 < kB; ks += 2) {
      LDG4A(Y0, Y1, Y2, Y3);              // prefetch ks+1 BEFORE consuming ks
      LOADF_P(Fy0, Fy1);
      STEP8(X0, X1, X2, X3, Fx0, Fx1);    // ks
      LDG4A(X0, X1, X2, X3);              // prefetch ks+2
      LOADF_P(Fx0, Fx1);
      STEP8(Y0, Y1, Y2, Y3, Fy0, Fy1);    // ks+1
    }
    LDG4A(Y0, Y1, Y2, Y3);
    LOADF_P(Fy0, Fy1);
    STEP8(X0, X1, X2, X3, Fx0, Fx1);
    STEP8(Y0, Y1, Y2, Y3, Fy0, Fy1);

    // ---- per-row max: lags lane-local -> in-register fold + 1 shuffle ----
    float a0 = fmaxf(fmaxf(z00[0], z01[0]), fmaxf(z02[0], z03[0]));
    float a1 = fmaxf(fmaxf(z10[0], z11[0]), fmaxf(z12[0], z13[0]));
#pragma unroll
    for (int q = 1; q < 16; ++q) {
      a0 = fmaxf(a0, fmaxf(fmaxf(z00[q], z01[q]), fmaxf(z02[q], z03[q])));
      a1 = fmaxf(a1, fmaxf(fmaxf(z10[q], z11[q]), fmaxf(z12[q], z13[q])));
    }
    a0 = fmaxf(a0, __shfl_xor(a0, 32, 64));
    a1 = fmaxf(a1, __shfl_xor(a1, 32, 64));
    if (l5 == 0) {
      red[pc][rw * 64 + l31] = a0;        // rows rw*64 + 0..31
      red[pc][rw * 64 + 32 + l31] = a1;   // rows rw*64 + 32..63
    }
    __syncthreads();
    part[(tid * 16 + blk) * 256 + j] = f2bf(red[pc][tid]);
    // no 2nd barrier: the other phase writes red[pc^1]; ordering via its barrier
  }
}

// ---------------- per-row CE: dist, logsumexp, pick target; atomic sum ----------------
__global__ __launch_bounds__(256) void loss_kernel(
    const unsigned short* __restrict__ part, const float* __restrict__ s1,
    const float* __restrict__ s2, const int* __restrict__ speeds,
    float* __restrict__ out) {
  int i = blockIdx.x;
  int jt = threadIdx.x;
  unsigned short um = part[(i * 16 + 0) * 256 + jt];
  float m = __builtin_bit_cast(float, ((unsigned int)um) << 16);
#pragma unroll
  for (int b = 1; b < 16; ++b) {
    unsigned short ub = part[(i * 16 + b) * 256 + jt];
    m = fmaxf(m, __builtin_bit_cast(float, ((unsigned int)ub) << 16));
  }
  float p = s1[i] * s2[jt];
  p = (p == 0.0f) ? 1.0f : p;
  float d = m / (p * 1023.0f);

  float t = d;
  for (int mk = 1; mk <= 32; mk <<= 1) t = fmaxf(t, __shfl_xor(t, mk, 64));
  __shared__ float wmax[4], wsum[4], sel;
  if ((jt & 63) == 0) wmax[jt >> 6] = t;
  if (jt == speeds[i]) sel = d;
  __syncthreads();
  float rmax = fmaxf(fmaxf(wmax[0], wmax[1]), fmaxf(wmax[2], wmax[3]));
  float e = expf(d - rmax);
  for (int mk = 1; mk <= 32; mk <<= 1) e += __shfl_xor(e, mk, 64);
  if ((jt & 63) == 0) wsum[jt >> 6] = e;
  __syncthreads();
  if (jt == 0) {
    float sum = wsum[0] + wsum[1] + wsum[2] + wsum[3];
    atomicAdd(out, rmax + logf(sum) - sel);
  }
}

extern "C" void kernel_launch(void* const* d_in, const int* in_sizes, int n_in,
                              void* d_out, int out_size, void* d_ws, size_t ws_size,
                              hipStream_t stream) {
  (void)in_sizes; (void)n_in; (void)out_size; (void)ws_size;
  const float* zis = (const float*)d_in[0];
  const float* zjs = (const float*)d_in[1];
  const int* speeds = (const int*)d_in[2];
  float* out = (float*)d_out;

  char* ws = (char*)d_ws;
  unsigned int* f1p4 = (unsigned int*)ws;                          // 128 KB packed fp4 A
  unsigned int* gpz4 = (unsigned int*)(ws + 131072);               // 260 KB padded fp4 rows
  float* s1 = (float*)(ws + 131072 + 266240);                      // 1 KB
  float* s2 = (float*)(ws + 131072 + 266240 + 1024);               // 1 KB
  unsigned short* part = (unsigned short*)(ws + 131072 + 266240 + 2048);  // 2 MB bf16

  prep_kernel<<<512, 256, 0, stream>>>(zis, zjs, f1p4, gpz4, s1, s2, out);
  corr_kernel<<<2048, 256, 0, stream>>>(f1p4, gpz4, part);
  loss_kernel<<<256, 256, 0, stream>>>(part, s1, s2, speeds, out);
}

// Round 20
// 51.465 us; speedup vs baseline: 1.2195x; 1.0280x over previous
//
#include <hip/hip_runtime.h>
#include <hip/hip_bf16.h>

#define M_ROWS 256
#define T_LEN  1024
#define NLAG   2048
#define CPYB   656    // bytes per copy slot = 16*41 (16B-aligned bases); 164 words == 4 mod 32
#define CPCH   39     // 16B chunks of data per copy (39*16 = 624)
#define NCOPY4 32
#define GPZW4  260    // u32 words per padded fp4 row (128 data | 128 zero | 4 wrap)

typedef __attribute__((ext_vector_type(4)))  unsigned int u32x4;
typedef __attribute__((ext_vector_type(8)))  int          i32x8;
typedef __attribute__((ext_vector_type(16))) float        f32x16;

static __device__ __forceinline__ unsigned short f2bf(float f) {
  unsigned int u = __builtin_bit_cast(unsigned int, f);
  u += 0x7FFFu + ((u >> 16) & 1u);   // RNE
  return (unsigned short)(u >> 16);
}

// nearest fp4 e2m1 level: {0,.5,1,1.5,2,3,4,6}, midpoint thresholds
static __device__ __forceinline__ unsigned int fp4enc(float c) {
  float a = fabsf(c);
  unsigned int code = (unsigned int)(a >= 0.25f) + (unsigned int)(a >= 0.75f) +
                      (unsigned int)(a >= 1.25f) + (unsigned int)(a >= 1.75f) +
                      (unsigned int)(a >= 2.5f)  + (unsigned int)(a >= 3.5f) +
                      (unsigned int)(a >= 5.0f);
  return code | ((__builtin_bit_cast(unsigned int, c) >> 28) & 8u);
}

// ---------------- prep: center rows, fp4-ify, std(ddof=1) ----------------
// f1 -> packed fp4 fragments f1p4[[ks][l5][row][4w]]; f2 -> padded fp4 rows gpz4[256][260w]
__global__ __launch_bounds__(256) void prep_kernel(
    const float* __restrict__ zis, const float* __restrict__ zjs,
    unsigned int* __restrict__ f1p4, unsigned int* __restrict__ gpz4,
    float* __restrict__ s1, float* __restrict__ s2, float* __restrict__ out) {
  int r = blockIdx.x;  // 0..511
  const float* src = (r < M_ROWS) ? (zis + r * T_LEN) : (zjs + (r - M_ROWS) * T_LEN);
  int t = threadIdx.x;
  if (r == 0 && t == 0) out[0] = 0.0f;
  float4 v = reinterpret_cast<const float4*>(src)[t];
  float ls = v.x + v.y + v.z + v.w;
  for (int m = 1; m <= 32; m <<= 1) ls += __shfl_xor(ls, m, 64);
  __shared__ float red[4];
  __shared__ float red2[4];
  if ((t & 63) == 0) red[t >> 6] = ls;
  __syncthreads();
  float mean = (red[0] + red[1] + red[2] + red[3]) * (1.0f / 1024.0f);
  float c0 = v.x - mean, c1 = v.y - mean, c2 = v.z - mean, c3 = v.w - mean;
  float ss = c0 * c0 + c1 * c1 + c2 * c2 + c3 * c3;
  for (int m = 1; m <= 32; m <<= 1) ss += __shfl_xor(ss, m, 64);
  if ((t & 63) == 0) red2[t >> 6] = ss;
  __syncthreads();
  float sd = sqrtf((red2[0] + red2[1] + red2[2] + red2[3]) * (1.0f / 1023.0f));

  unsigned int h16 = fp4enc(c0) | (fp4enc(c1) << 4) | (fp4enc(c2) << 8) | (fp4enc(c3) << 12);
  unsigned int other = (unsigned int)__shfl_xor((int)h16, 1, 64);
  unsigned int word = h16 | (other << 16);   // valid on even t: elems 8*(t/2)..+7

  if (r < M_ROWS) {
    if (t == 0) s1[r] = sd;
    if (!(t & 1)) {
      int ks = t >> 4, l5 = (t >> 3) & 1, w = (t & 7) >> 1;
      f1p4[((ks * 2 + l5) * 256 + r) * 4 + w] = word;
    }
  } else {
    int j = r - M_ROWS;
    if (t == 0) s2[j] = sd;
    if (!(t & 1)) gpz4[j * GPZW4 + (t >> 1)] = word;       // data words 0..127
    if (t >= 128) gpz4[j * GPZW4 + t] = 0u;                // zero words 128..255
    if (!(t & 1) && (t >> 1) < 4) gpz4[j * GPZW4 + 256 + (t >> 1)] = word;  // wrap tail
  }
}

// ---- fully-unrolled phase: all G addresses = 1 base VGPR + compile-time immediates ----
// byte(ks,l5,lf,pc) = 32ks + 16l5 - 16lf - 64BP + 48 + 512pc  (in [0,624], proven R16/R17)
template <int BP, int PC>
__device__ __forceinline__ void run_and_store(
    const unsigned char* __restrict__ ldsB, int gb_lane,
    const unsigned int* __restrict__ fbase,
    float (*red)[256], unsigned short* __restrict__ part,
    int j, int tid, int rw, int l5, int l31) {
  constexpr int KA = PC ? 0 : 2 * BP;
  constexpr int N  = (PC ? (2 * BP + 2) : 16) - KA;   // even, >= 2
  constexpr int PBASE = PC ? (512 - 64 * BP) : 0;
  constexpr int BLK = PC ? (BP + 8) : BP;

  const unsigned char* gB = ldsB + gb_lane;   // per-lane VGPR base; rest is immediate
  const unsigned int* fp = fbase + KA * 2048;

  f32x16 z00, z01, z02, z03, z10, z11, z12, z13;
#pragma unroll
  for (int q = 0; q < 16; ++q) {
    z00[q] = 0.f; z01[q] = 0.f; z02[q] = 0.f; z03[q] = 0.f;
    z10[q] = 0.f; z11[q] = 0.f; z12[q] = 0.f; z13[q] = 0.f;
  }

  i32x8 X0 = {0,0,0,0,0,0,0,0}, X1 = {0,0,0,0,0,0,0,0};
  i32x8 X2 = {0,0,0,0,0,0,0,0}, X3 = {0,0,0,0,0,0,0,0};
  i32x8 Y0 = {0,0,0,0,0,0,0,0}, Y1 = {0,0,0,0,0,0,0,0};
  i32x8 Y2 = {0,0,0,0,0,0,0,0}, Y3 = {0,0,0,0,0,0,0,0};
  i32x8 Fx0 = {0,0,0,0,0,0,0,0}, Fx1 = {0,0,0,0,0,0,0,0};
  i32x8 Fy0 = {0,0,0,0,0,0,0,0}, Fy1 = {0,0,0,0,0,0,0,0};

#define LXU(S) {                                                          \
    ((u32x4*)&X0)[0] = *(const u32x4*)(gB + PBASE + 32 * (S) + 48);       \
    ((u32x4*)&X1)[0] = *(const u32x4*)(gB + PBASE + 32 * (S) + 32);       \
    ((u32x4*)&X2)[0] = *(const u32x4*)(gB + PBASE + 32 * (S) + 16);       \
    ((u32x4*)&X3)[0] = *(const u32x4*)(gB + PBASE + 32 * (S));            \
    ((u32x4*)&Fx0)[0] = *(const u32x4*)(fp + (S) * 2048);                 \
    ((u32x4*)&Fx1)[0] = *(const u32x4*)(fp + (S) * 2048 + 128); }
#define LYU(S) {                                                          \
    ((u32x4*)&Y0)[0] = *(const u32x4*)(gB + PBASE + 32 * (S) + 48);       \
    ((u32x4*)&Y1)[0] = *(const u32x4*)(gB + PBASE + 32 * (S) + 32);       \
    ((u32x4*)&Y2)[0] = *(const u32x4*)(gB + PBASE + 32 * (S) + 16);       \
    ((u32x4*)&Y3)[0] = *(const u32x4*)(gB + PBASE + 32 * (S));            \
    ((u32x4*)&Fy0)[0] = *(const u32x4*)(fp + (S) * 2048);                 \
    ((u32x4*)&Fy1)[0] = *(const u32x4*)(fp + (S) * 2048 + 128); }
#define MXU() {                                                                               \
    z00 = __builtin_amdgcn_mfma_scale_f32_32x32x64_f8f6f4(X0, Fx0, z00, 4, 4, 0, 127, 0, 127); \
    z10 = __builtin_amdgcn_mfma_scale_f32_32x32x64_f8f6f4(X0, Fx1, z10, 4, 4, 0, 127, 0, 127); \
    z01 = __builtin_amdgcn_mfma_scale_f32_32x32x64_f8f6f4(X1, Fx0, z01, 4, 4, 0, 127, 0, 127); \
    z11 = __builtin_amdgcn_mfma_scale_f32_32x32x64_f8f6f4(X1, Fx1, z11, 4, 4, 0, 127, 0, 127); \
    z02 = __builtin_amdgcn_mfma_scale_f32_32x32x64_f8f6f4(X2, Fx0, z02, 4, 4, 0, 127, 0, 127); \
    z12 = __builtin_amdgcn_mfma_scale_f32_32x32x64_f8f6f4(X2, Fx1, z12, 4, 4, 0, 127, 0, 127); \
    z03 = __builtin_amdgcn_mfma_scale_f32_32x32x64_f8f6f4(X3, Fx0, z03, 4, 4, 0, 127, 0, 127); \
    z13 = __builtin_amdgcn_mfma_scale_f32_32x32x64_f8f6f4(X3, Fx1, z13, 4, 4, 0, 127, 0, 127); }
#define MYU() {                                                                               \
    z00 = __builtin_amdgcn_mfma_scale_f32_32x32x64_f8f6f4(Y0, Fy0, z00, 4, 4, 0, 127, 0, 127); \
    z10 = __builtin_amdgcn_mfma_scale_f32_32x32x64_f8f6f4(Y0, Fy1, z10, 4, 4, 0, 127, 0, 127); \
    z01 = __builtin_amdgcn_mfma_scale_f32_32x32x64_f8f6f4(Y1, Fy0, z01, 4, 4, 0, 127, 0, 127); \
    z11 = __builtin_amdgcn_mfma_scale_f32_32x32x64_f8f6f4(Y1, Fy1, z11, 4, 4, 0, 127, 0, 127); \
    z02 = __builtin_amdgcn_mfma_scale_f32_32x32x64_f8f6f4(Y2, Fy0, z02, 4, 4, 0, 127, 0, 127); \
    z12 = __builtin_amdgcn_mfma_scale_f32_32x32x64_f8f6f4(Y2, Fy1, z12, 4, 4, 0, 127, 0, 127); \
    z03 = __builtin_amdgcn_mfma_scale_f32_32x32x64_f8f6f4(Y3, Fy0, z03, 4, 4, 0, 127, 0, 127); \
    z13 = __builtin_amdgcn_mfma_scale_f32_32x32x64_f8f6f4(Y3, Fy1, z13, 4, 4, 0, 127, 0, 127); }

  LXU(0);
#pragma unroll
  for (int t = 0; t < N - 2; t += 2) {
    LYU(t + 1);      // prefetch BEFORE consuming
    MXU();
    LXU(t + 2);
    MYU();
  }
  LYU(N - 1);
  MXU();
  MYU();

#undef LXU
#undef LYU
#undef MXU
#undef MYU

  // ---- per-row max: lags lane-local -> in-register fold + 1 shuffle ----
  float a0 = fmaxf(fmaxf(z00[0], z01[0]), fmaxf(z02[0], z03[0]));
  float a1 = fmaxf(fmaxf(z10[0], z11[0]), fmaxf(z12[0], z13[0]));
#pragma unroll
  for (int q = 1; q < 16; ++q) {
    a0 = fmaxf(a0, fmaxf(fmaxf(z00[q], z01[q]), fmaxf(z02[q], z03[q])));
    a1 = fmaxf(a1, fmaxf(fmaxf(z10[q], z11[q]), fmaxf(z12[q], z13[q])));
  }
  a0 = fmaxf(a0, __shfl_xor(a0, 32, 64));
  a1 = fmaxf(a1, __shfl_xor(a1, 32, 64));
  if (l5 == 0) {
    red[PC][rw * 64 + l31] = a0;        // rows rw*64 + 0..31
    red[PC][rw * 64 + 32 + l31] = a1;   // rows rw*64 + 32..63
  }
  __syncthreads();
  part[(tid * 16 + BLK) * 256 + j] = f2bf(red[PC][tid]);
  // no 2nd barrier: other phase writes red[PC^1]; ordering via its barrier (R17-proven)
}

template <int BP>
__device__ __forceinline__ void do_pair(
    const unsigned char* __restrict__ ldsB, int gb_lane,
    const unsigned int* __restrict__ fbase,
    float (*red)[256], unsigned short* __restrict__ part,
    int j, int tid, int rw, int l5, int l31) {
  run_and_store<BP, 0>(ldsB, gb_lane, fbase, red, part, j, tid, rw, l5, l31);
  run_and_store<BP, 1>(ldsB, gb_lane, fbase, red, part, j, tid, rw, l5, l31);
}

// ---------------- Toeplitz-GEMM correlation (MX-fp4, range-compressed, full unroll) ----
// grid: wg = bp*256 + j ; 2048 wgs, 256 threads = 4 waves (wave rw = row quarter).
// wg does blk pair (bp, bp+8): 18 k64-steps, uniform. Wave tile 64 rows x 128 lags.
__global__ __launch_bounds__(256, 2) void corr_kernel(
    const unsigned int* __restrict__ f1p4,
    const unsigned int* __restrict__ gpz4,
    unsigned short* __restrict__ part) {
  __shared__ __align__(16) unsigned char ldsB[NCOPY4 * CPYB];   // 20992 B
  __shared__ float red[2][256];                                 // phase-indexed dbuf

  int wg = blockIdx.x;
  int j = wg & 255;
  int bp = wg >> 8;         // 0..7

  int tid = threadIdx.x;
  int lane = tid & 63;
  int rw = tid >> 6;        // wave id = row quarter
  int l5 = lane >> 5;
  int l31 = lane & 31;

  // ---- build 32 range-compressed fp4 copies: 1248 16B chunks ----
  {
    const unsigned int* gj = gpz4 + j * GPZW4;
#pragma unroll
    for (int m = 0; m < 5; ++m) {
      int ch = m * 256 + tid;
      if (ch < NCOPY4 * CPCH) {
        int cp = ch / CPCH;           // magic-mul
        int cc = ch - cp * CPCH;
        int s = 32 * cc - 96 - cp;    // source elem of chunk start: x0 - cp
        int m0 = s + ((s < 0) ? 2048 : 0);
        int wb = m0 >> 3;
        int sh = (m0 & 7) << 2;
        unsigned int w0 = gj[wb], w1 = gj[wb + 1], w2 = gj[wb + 2],
                     w3 = gj[wb + 3], w4 = gj[wb + 4];
        u32x4 o;
        if (sh) {
          o[0] = (w0 >> sh) | (w1 << (32 - sh));
          o[1] = (w1 >> sh) | (w2 << (32 - sh));
          o[2] = (w2 >> sh) | (w3 << (32 - sh));
          o[3] = (w3 >> sh) | (w4 << (32 - sh));
        } else {
          o[0] = w0; o[1] = w1; o[2] = w2; o[3] = w3;
        }
        *reinterpret_cast<u32x4*>(ldsB + cp * CPYB + cc * 16) = o;
      }
    }
  }
  __syncthreads();

  // F (rows, MFMA-B): word idx ((ks*2+l5)*256 + row)*4
  const unsigned int* fbase = f1p4 + l5 * 1024 + ((rw * 64 + l31) << 2);
  int gb_lane = l31 * CPYB + 16 * l5;   // per-lane G base (everything else is immediate)

  switch (bp) {
    case 0: do_pair<0>(ldsB, gb_lane, fbase, red, part, j, tid, rw, l5, l31); break;
    case 1: do_pair<1>(ldsB, gb_lane, fbase, red, part, j, tid, rw, l5, l31); break;
    case 2: do_pair<2>(ldsB, gb_lane, fbase, red, part, j, tid, rw, l5, l31); break;
    case 3: do_pair<3>(ldsB, gb_lane, fbase, red, part, j, tid, rw, l5, l31); break;
    case 4: do_pair<4>(ldsB, gb_lane, fbase, red, part, j, tid, rw, l5, l31); break;
    case 5: do_pair<5>(ldsB, gb_lane, fbase, red, part, j, tid, rw, l5, l31); break;
    case 6: do_pair<6>(ldsB, gb_lane, fbase, red, part, j, tid, rw, l5, l31); break;
    default: do_pair<7>(ldsB, gb_lane, fbase, red, part, j, tid, rw, l5, l31); break;
  }
}

// ---------------- per-row CE: dist, logsumexp, pick target; atomic sum ----------------
__global__ __launch_bounds__(256) void loss_kernel(
    const unsigned short* __restrict__ part, const float* __restrict__ s1,
    const float* __restrict__ s2, const int* __restrict__ speeds,
    float* __restrict__ out) {
  int i = blockIdx.x;
  int jt = threadIdx.x;
  unsigned short um = part[(i * 16 + 0) * 256 + jt];
  float m = __builtin_bit_cast(float, ((unsigned int)um) << 16);
#pragma unroll
  for (int b = 1; b < 16; ++b) {
    unsigned short ub = part[(i * 16 + b) * 256 + jt];
    m = fmaxf(m, __builtin_bit_cast(float, ((unsigned int)ub) << 16));
  }
  float p = s1[i] * s2[jt];
  p = (p == 0.0f) ? 1.0f : p;
  float d = m / (p * 1023.0f);

  float t = d;
  for (int mk = 1; mk <= 32; mk <<= 1) t = fmaxf(t, __shfl_xor(t, mk, 64));
  __shared__ float wmax[4], wsum[4], sel;
  if ((jt & 63) == 0) wmax[jt >> 6] = t;
  if (jt == speeds[i]) sel = d;
  __syncthreads();
  float rmax = fmaxf(fmaxf(wmax[0], wmax[1]), fmaxf(wmax[2], wmax[3]));
  float e = expf(d - rmax);
  for (int mk = 1; mk <= 32; mk <<= 1) e += __shfl_xor(e, mk, 64);
  if ((jt & 63) == 0) wsum[jt >> 6] = e;
  __syncthreads();
  if (jt == 0) {
    float sum = wsum[0] + wsum[1] + wsum[2] + wsum[3];
    atomicAdd(out, rmax + logf(sum) - sel);
  }
}

extern "C" void kernel_launch(void* const* d_in, const int* in_sizes, int n_in,
                              void* d_out, int out_size, void* d_ws, size_t ws_size,
                              hipStream_t stream) {
  (void)in_sizes; (void)n_in; (void)out_size; (void)ws_size;
  const float* zis = (const float*)d_in[0];
  const float* zjs = (const float*)d_in[1];
  const int* speeds = (const int*)d_in[2];
  float* out = (float*)d_out;

  char* ws = (char*)d_ws;
  unsigned int* f1p4 = (unsigned int*)ws;                          // 128 KB packed fp4 A
  unsigned int* gpz4 = (unsigned int*)(ws + 131072);               // 260 KB padded fp4 rows
  float* s1 = (float*)(ws + 131072 + 266240);                      // 1 KB
  float* s2 = (float*)(ws + 131072 + 266240 + 1024);               // 1 KB
  unsigned short* part = (unsigned short*)(ws + 131072 + 266240 + 2048);  // 2 MB bf16

  prep_kernel<<<512, 256, 0, stream>>>(zis, zjs, f1p4, gpz4, s1, s2, out);
  corr_kernel<<<2048, 256, 0, stream>>>(f1p4, gpz4, part);
  loss_kernel<<<256, 256, 0, stream>>>(part, s1, s2, speeds, out);
}